// Round 6
// baseline (225.688 us; speedup 1.0000x reference)
//
#include <hip/hip_runtime.h>

// VectorQuantizer on MI355X — MFMA f16-split, z-in-registers, B-direct-from-L2.
// z: [64,1024,256] f32 -> N=65536 rows, D=256. codebook: [1024,256] f32, K=1024.
// Outputs (concat flat): z_q (16777216 f32), loss (1), perplexity (1).
//
// Precision: v = hi + lo/2048 (f16 each); dot = hh + (h*l' + l*h')/2048.
// Round-6: no LDS staging / no barriers in the K loop. Codebook image is 1 MB,
// L1/L2-resident; B fragments load straight to VGPRs from a transposed image:
//   unit u = chunk*2 + kh (64 codes x 128 k), 32768 B each:
//   addr = u*32768 + g*2048 + hl*1024 + code_local*16   (g = k_granule 0..15)
// A wave's (lh,l31) lanes hit two contiguous 512B runs per load — coalesced.

#define N_ROWS 65536
#define DIM    256
#define K_CODES 1024
#define BETA   0.001f

#define BM      128                // rows per block
#define NBLOCKS (N_ROWS / BM)      // 512
#define NTHREADS 512
#define UNIT_BYTES 32768

#define LO_SCALE 2048.0f
#define LO_INV   (1.0f / 2048.0f)

// ws layout:
//   float[0,1024)    cnorm
//   int  [1024,2048) counts
//   float[2048,4096) ploss
//   byte 16384 ...   transposed codebook image, 32 units x 32768 B = 1 MB
#define WS_CBIMG_OFF 16384
#define WS_NEED (WS_CBIMG_OFF + 32 * UNIT_BYTES)

typedef _Float16 f16x8 __attribute__((ext_vector_type(8)));
typedef float f32x16 __attribute__((ext_vector_type(16)));

// ---------------- prep kernels ----------------

__global__ void cnorm_kernel(const float* __restrict__ cb, float* __restrict__ cnorm) {
    int k = blockIdx.x * blockDim.x + threadIdx.x;
    if (k >= K_CODES) return;
    const float4* row = (const float4*)(cb + (size_t)k * DIM);
    float s = 0.f;
#pragma unroll
    for (int j = 0; j < DIM / 4; ++j) {
        float4 v = row[j];
        s = fmaf(v.x, v.x, s);
        s = fmaf(v.y, v.y, s);
        s = fmaf(v.z, v.z, s);
        s = fmaf(v.w, v.w, s);
    }
    cnorm[k] = s;
}

// Codebook f32 -> f16 hi/lo(scaled), transposed image:
// unit = (c>>6)*2 + kh ; within unit: g*2048 + hl*1024 + (c&63)*16.
__global__ void cb_prep(const float* __restrict__ cb, char* __restrict__ img) {
    int idx = blockIdx.x * blockDim.x + threadIdx.x;   // 0..32767
    int c   = idx >> 5;          // code 0..1023
    int g32 = idx & 31;          // granule of 8 floats over 256 dims
    const float4* src = (const float4*)(cb + (size_t)c * DIM + g32 * 8);
    float4 v0 = src[0], v1 = src[1];
    float vv[8] = {v0.x, v0.y, v0.z, v0.w, v1.x, v1.y, v1.z, v1.w};
    f16x8 hi, lo;
#pragma unroll
    for (int j = 0; j < 8; ++j) {
        _Float16 h = (_Float16)vv[j];
        hi[j] = h;
        lo[j] = (_Float16)((vv[j] - (float)h) * LO_SCALE);
    }
    int kh = g32 >> 4;
    int gl = g32 & 15;           // granule within the 128-k half
    int cl = c & 63;
    int unit = (c >> 6) * 2 + kh;
    size_t off = (size_t)unit * UNIT_BYTES + (size_t)gl * 2048 + (size_t)cl * 16;
    *(f16x8*)(img + off) = hi;            // hl = 0
    *(f16x8*)(img + off + 1024) = lo;     // hl = 1
}

// ---------------- MFMA main kernel ----------------

#define COMPUTE_HALF(KH)                                                             \
    {                                                                                \
        const char* ub = img + (size_t)(chunk * 2 + (KH)) * UNIT_BYTES + crow16;     \
        f16x8 bh[8], bl[8];                                                          \
        _Pragma("unroll")                                                            \
        for (int ks = 0; ks < 8; ++ks) {                                             \
            int g = ks * 2 + lh;                                                     \
            bh[ks] = *(const f16x8*)(ub + g * 2048);                                 \
            bl[ks] = *(const f16x8*)(ub + g * 2048 + 1024);                          \
        }                                                                            \
        _Pragma("unroll")                                                            \
        for (int ks = 0; ks < 8; ++ks) {                                             \
            f16x8 ah = zh[(KH) * 8 + ks];                                            \
            f16x8 al = zl[(KH) * 8 + ks];                                            \
            acc_hh = __builtin_amdgcn_mfma_f32_32x32x16_f16(ah, bh[ks], acc_hh, 0, 0, 0); \
            f32x16& ax = (ks & 1) ? acc_xo : acc_xe;                                 \
            ax = __builtin_amdgcn_mfma_f32_32x32x16_f16(ah, bl[ks], ax, 0, 0, 0);    \
            ax = __builtin_amdgcn_mfma_f32_32x32x16_f16(al, bh[ks], ax, 0, 0, 0);    \
        }                                                                            \
    }

__global__ __launch_bounds__(NTHREADS, 2)
void vq_main_mfma(const float* __restrict__ z, const float* __restrict__ cb,
                  const char* __restrict__ img, const float* __restrict__ cnorm,
                  float* __restrict__ out, int* __restrict__ counts,
                  float* __restrict__ ploss) {
    __shared__ unsigned long long bkey2[BM][2];
    __shared__ int bests[BM];
    __shared__ float red[NTHREADS];

    const int tid  = threadIdx.x;
    const int lane = tid & 63;
    const int w    = tid >> 6;      // wave 0..7
    const int wr   = w >> 1;        // row-tile 0..3 (32 rows each)
    const int wc   = w & 1;         // col-half of 64-code chunk
    const int l31  = lane & 31;
    const int lh   = lane >> 5;
    const int r0   = blockIdx.x * BM;

    // ---- z fragments -> registers (f16 hi/lo, MFMA A layout) ----
    const int zrow = wr * 32 + l31;
    f16x8 zh[16], zl[16];
    {
        const float* zr = z + (size_t)(r0 + zrow) * DIM;
#pragma unroll
        for (int gi = 0; gi < 16; ++gi) {
            int g = gi * 2 + lh;                 // granule parity = lh
            float4 v0 = *(const float4*)(zr + g * 8);
            float4 v1 = *(const float4*)(zr + g * 8 + 4);
            float vv[8] = {v0.x, v0.y, v0.z, v0.w, v1.x, v1.y, v1.z, v1.w};
            f16x8 hi, lo;
#pragma unroll
            for (int j = 0; j < 8; ++j) {
                _Float16 h = (_Float16)vv[j];
                hi[j] = h;
                lo[j] = (_Float16)((vv[j] - (float)h) * LO_SCALE);
            }
            zh[gi] = hi;
            zl[gi] = lo;
        }
    }

    f32x16 acc_hh, acc_xe, acc_xo;
#pragma unroll
    for (int e = 0; e < 16; ++e) { acc_hh[e] = 0.f; acc_xe[e] = 0.f; acc_xo[e] = 0.f; }
    unsigned long long bestk[16];
#pragma unroll
    for (int e = 0; e < 16; ++e) bestk[e] = ~0ull;

    const int crow = wc * 32 + l31;              // code row within 64-chunk
    const int crow16 = crow * 16;

#pragma unroll 1
    for (int chunk = 0; chunk < 16; ++chunk) {
        int col = chunk * 64 + crow;
        float cn = cnorm[col];

        COMPUTE_HALF(0)
        COMPUTE_HALF(1)

        // ---- fold chunk: score = ||c||^2 - 2 z.c ----
#pragma unroll
        for (int rg = 0; rg < 16; ++rg) {
            float dot = fmaf(acc_xe[rg] + acc_xo[rg], LO_INV, acc_hh[rg]);
            float s = fmaf(-2.0f, dot, cn);
            unsigned uu = __float_as_uint(s);
            uu = (uu & 0x80000000u) ? ~uu : (uu | 0x80000000u);
            unsigned long long key = ((unsigned long long)uu << 32) | (unsigned)col;
            bestk[rg] = key < bestk[rg] ? key : bestk[rg];
        }
#pragma unroll
        for (int e = 0; e < 16; ++e) { acc_hh[e] = 0.f; acc_xe[e] = 0.f; acc_xo[e] = 0.f; }
    }

    // ---- reduce best over the 32 lanes of each half (codes axis) ----
#pragma unroll
    for (int rg = 0; rg < 16; ++rg) {
        unsigned long long bk = bestk[rg];
#pragma unroll
        for (int s = 1; s < 32; s <<= 1) {
            unsigned long long o = __shfl_xor(bk, s, 64);
            bk = o < bk ? o : bk;
        }
        bestk[rg] = bk;
    }
    if (l31 == 0) {
#pragma unroll
        for (int rg = 0; rg < 16; ++rg) {
            int rl = (rg & 3) + 8 * (rg >> 2) + 4 * lh;   // C/D row mapping (m74/m101)
            bkey2[wr * 32 + rl][wc] = bestk[rg];
        }
    }
    __syncthreads();
    if (tid < BM) {
        unsigned long long a = bkey2[tid][0];
        unsigned long long b2 = bkey2[tid][1];
        bests[tid] = (int)((a < b2 ? a : b2) & 0xffffffffu);
    }
    __syncthreads();

    // ---- epilogue: gather, straight-through output, loss, histogram ----
    const int r = tid >> 2;        // row 0..127
    const int q = tid & 3;
    const int bidx = bests[r];
    const float* crow_g = cb + (size_t)bidx * DIM;
    const float* zrow_g = z + (size_t)(r0 + r) * DIM;
    float* orow = out + (size_t)(r0 + r) * DIM;
    float lsum = 0.f;
#pragma unroll
    for (int j = 0; j < 16; ++j) {
        int g4 = j * 4 + q;                     // float4 index; 4 lanes -> 64B line
        float4 c4 = *(const float4*)(crow_g + g4 * 4);
        float4 z4 = *(const float4*)(zrow_g + g4 * 4);
        float4 o;
        float dx = c4.x - z4.x; o.x = z4.x + dx; lsum = fmaf(dx, dx, lsum);
        float dy = c4.y - z4.y; o.y = z4.y + dy; lsum = fmaf(dy, dy, lsum);
        float dz = c4.z - z4.z; o.z = z4.z + dz; lsum = fmaf(dz, dz, lsum);
        float dw = c4.w - z4.w; o.w = z4.w + dw; lsum = fmaf(dw, dw, lsum);
        *(float4*)(orow + g4 * 4) = o;
    }
    if (tid < BM) atomicAdd(&counts[bests[tid]], 1);

    red[tid] = lsum;
    __syncthreads();
    for (int s = NTHREADS / 2; s > 0; s >>= 1) {
        if (tid < s) red[tid] += red[tid + s];
        __syncthreads();
    }
    if (tid == 0) ploss[blockIdx.x] = red[0];
}

// ---------------- fallback fp32 kernel (round-1, known-good) ----------------

#define FBM     32
#define FCHUNK  512
#define FDSTAGE 16
#define FCS_PAD 20
#define FNBLOCKS (N_ROWS / FBM)   // 2048

__global__ __launch_bounds__(256, 2)
void vq_main_fp32(const float* __restrict__ z, const float* __restrict__ cb,
                  const float* __restrict__ cnorm, float* __restrict__ out,
                  int* __restrict__ counts, float* __restrict__ ploss) {
    __shared__ float zs[FBM][DIM];
    __shared__ float cs[FCHUNK][FCS_PAD];
    __shared__ int   bests[FBM];
    __shared__ float red[256];

    const int tid = threadIdx.x;
    const int tx  = tid & 63;
    const int ty  = tid >> 6;
    const int r0  = blockIdx.x * FBM;

    {
        const float4* zg  = (const float4*)(z + (size_t)r0 * DIM);
        float4*       zsv = (float4*)&zs[0][0];
#pragma unroll
        for (int j = 0; j < (FBM * DIM / 4) / 256; ++j)
            zsv[tid + 256 * j] = zg[tid + 256 * j];
    }

    unsigned long long best[8];
#pragma unroll
    for (int i = 0; i < 8; ++i) best[i] = ~0ull;

    for (int cb0 = 0; cb0 < K_CODES; cb0 += FCHUNK) {
        float acc[8][8];
#pragma unroll
        for (int i = 0; i < 8; ++i)
#pragma unroll
            for (int m = 0; m < 8; ++m) acc[i][m] = 0.f;

        for (int sd = 0; sd < DIM / FDSTAGE; ++sd) {
            __syncthreads();
#pragma unroll
            for (int j = 0; j < 8; ++j) {
                int f4i = tid + 256 * j;
                int c   = f4i >> 2;
                int qq  = f4i & 3;
                float4 v = *(const float4*)(cb + (size_t)(cb0 + c) * DIM + sd * FDSTAGE + qq * 4);
                *(float4*)&cs[c][qq * 4] = v;
            }
            __syncthreads();

#pragma unroll
            for (int dd4 = 0; dd4 < FDSTAGE / 4; ++dd4) {
                float4 zv[8], cv[8];
#pragma unroll
                for (int i = 0; i < 8; ++i)
                    zv[i] = *(const float4*)&zs[ty * 8 + i][sd * FDSTAGE + dd4 * 4];
#pragma unroll
                for (int m = 0; m < 8; ++m)
                    cv[m] = *(const float4*)&cs[tx + 64 * m][dd4 * 4];
#pragma unroll
                for (int i = 0; i < 8; ++i)
#pragma unroll
                    for (int m = 0; m < 8; ++m) {
                        float a = acc[i][m];
                        a = fmaf(zv[i].x, cv[m].x, a);
                        a = fmaf(zv[i].y, cv[m].y, a);
                        a = fmaf(zv[i].z, cv[m].z, a);
                        a = fmaf(zv[i].w, cv[m].w, a);
                        acc[i][m] = a;
                    }
            }
        }

#pragma unroll
        for (int m = 0; m < 8; ++m) {
            int   c  = cb0 + tx + 64 * m;
            float cn = cnorm[c];
#pragma unroll
            for (int i = 0; i < 8; ++i) {
                float s = fmaf(-2.f, acc[i][m], cn);
                unsigned u = __float_as_uint(s);
                u = (u & 0x80000000u) ? ~u : (u | 0x80000000u);
                unsigned long long key = ((unsigned long long)u << 32) | (unsigned)c;
                best[i] = key < best[i] ? key : best[i];
            }
        }
    }

#pragma unroll
    for (int i = 0; i < 8; ++i) {
        unsigned long long b = best[i];
#pragma unroll
        for (int s = 1; s < 64; s <<= 1) {
            unsigned long long o = __shfl_xor(b, s, 64);
            b = o < b ? o : b;
        }
        best[i] = b;
    }
    if (tx == 0)
#pragma unroll
        for (int i = 0; i < 8; ++i)
            bests[ty * 8 + i] = (int)(best[i] & 0xFFFFFFFFu);
    __syncthreads();

    const int r  = tid >> 3;
    const int lq = tid & 7;
    const int bidx = bests[r];
    const float4* crow = (const float4*)(cb + (size_t)bidx * DIM);
    const float4* zrow = (const float4*)&zs[r][0];
    float4*       orow = (float4*)(out + (size_t)(r0 + r) * DIM);
    float lsum = 0.f;
#pragma unroll
    for (int j = 0; j < 8; ++j) {
        int qg = lq + j * 8;
        float4 c4 = crow[qg];
        float4 z4 = zrow[qg];
        float4 o;
        float dx = c4.x - z4.x; o.x = z4.x + dx; lsum = fmaf(dx, dx, lsum);
        float dy = c4.y - z4.y; o.y = z4.y + dy; lsum = fmaf(dy, dy, lsum);
        float dz = c4.z - z4.z; o.z = z4.z + dz; lsum = fmaf(dz, dz, lsum);
        float dw = c4.w - z4.w; o.w = z4.w + dw; lsum = fmaf(dw, dw, lsum);
        orow[qg] = o;
    }
    if (tid < FBM) atomicAdd(&counts[bests[tid]], 1);

    red[tid] = lsum;
    __syncthreads();
    for (int s = 128; s > 0; s >>= 1) {
        if (tid < s) red[tid] += red[tid + s];
        __syncthreads();
    }
    if (tid == 0) ploss[blockIdx.x] = red[0];
}

// ---------------- finalize ----------------

__global__ void vq_final(const float* __restrict__ ploss, const int* __restrict__ counts,
                         const int* __restrict__ flg, float* __restrict__ out2, int np) {
    __shared__ float red[1024];
    const int t = threadIdx.x;

    float l = 0.f;
    for (int i = t; i < np; i += 1024) l += ploss[i];
    red[t] = l;
    __syncthreads();
    for (int s = 512; s > 0; s >>= 1) {
        if (t < s) red[t] += red[t + s];
        __syncthreads();
    }
    if (t == 0) {
        float loss = (red[0] / (float)((size_t)N_ROWS * DIM)) * (1.0f + BETA);
        if (flg[0] == 0) loss = 0.f;
        out2[0] = loss;
    }
    __syncthreads();

    float e = (float)counts[t] / (float)N_ROWS;
    red[t] = e * logf(e + 1e-10f);
    __syncthreads();
    for (int s = 512; s > 0; s >>= 1) {
        if (t < s) red[t] += red[t + s];
        __syncthreads();
    }
    if (t == 0) out2[1] = expf(-red[0]);
}

extern "C" void kernel_launch(void* const* d_in, const int* in_sizes, int n_in,
                              void* d_out, int out_size, void* d_ws, size_t ws_size,
                              hipStream_t stream) {
    const float* z   = (const float*)d_in[0];
    const float* cb  = (const float*)d_in[1];
    const int*   flg = (const int*)d_in[2];
    float* out = (float*)d_out;
    float* ws  = (float*)d_ws;

    float* cnorm  = ws;
    int*   counts = (int*)(ws + 1024);
    float* ploss  = ws + 2048;
    char*  cbimg  = (char*)d_ws + WS_CBIMG_OFF;

    hipMemsetAsync(counts, 0, K_CODES * sizeof(int), stream);
    cnorm_kernel<<<K_CODES / 256, 256, 0, stream>>>(cb, cnorm);

    if (ws_size >= (size_t)WS_NEED) {
        cb_prep<<<128, 256, 0, stream>>>(cb, cbimg);
        vq_main_mfma<<<NBLOCKS, NTHREADS, 0, stream>>>(z, cb, cbimg, cnorm, out, counts, ploss);
        vq_final<<<1, 1024, 0, stream>>>(ploss, counts, flg, out + (size_t)N_ROWS * DIM, NBLOCKS);
    } else {
        vq_main_fp32<<<FNBLOCKS, 256, 0, stream>>>(z, cb, cnorm, out, counts, ploss);
        vq_final<<<1, 1024, 0, stream>>>(ploss, counts, flg, out + (size_t)N_ROWS * DIM, FNBLOCKS);
    }
}